// Round 10
// baseline (499.036 us; speedup 1.0000x reference)
//
#include <hip/hip_runtime.h>
#include <hip/hip_bf16.h>

// NT-Xent loss — ABLATION ROUND. Symmetric panel-pair structure (528 blocks).
// Variants (REP=4 each so all exceed the ~43us fills and show in top-5):
//   kab_nostage : no global->LDS staging (reads garbage LDS)  -> staging cost
//   kab_nolds   : B operands from registers (no ds_reads)     -> LDS-read cost
//   kab_noexp   : no exp/colsum epilogue (rs += acc)          -> VALU/trans cost
//   kab_r8      : exact R8 baseline                           -> reference
//   kfix        : 4 waves x RT=4 (half LDS reads per MFMA)    -> candidate fix
// kfix runs LAST and fully overwrites partial -> d_out exact.

#define D      256
#define KC     8
#define PAN    32
#define NBLK   (PAN * (PAN + 1) / 2)   // 528
#define BN     32
#define NCH    8
#define SLOTS  32
#define CEXP   2.885390081777926f
#define E2     7.38905609893065f
#define FBLK   32
#define REP    4

typedef __bf16 bf16x8 __attribute__((ext_vector_type(8)));
typedef float  f32x4  __attribute__((ext_vector_type(4)));
typedef __attribute__((address_space(1))) const unsigned int* gas_t;
typedef __attribute__((address_space(3))) unsigned int*       las_t;

static __device__ __forceinline__ void gload_lds16(const void* g, void* l) {
    __builtin_amdgcn_global_load_lds((gas_t)(uintptr_t)g, (las_t)(uintptr_t)l, 16, 0, 0);
}

static __device__ __forceinline__ unsigned short f2bf(float x) {
    union { float f; unsigned u; } v; v.f = x;
    unsigned r = v.u + 0x7fffu + ((v.u >> 16) & 1u);
    return (unsigned short)(r >> 16);
}

// stage 16KB (32 rows x 512B); linear LDS dest, pre-swizzled source (rule 21)
#define STAGE_T(bufp, srcp, NTHR, NIT)                                    \
    do {                                                                  \
        const char* s_ = (const char*)(srcp);                             \
        char* d_ = (char*)(bufp);                                         \
        _Pragma("unroll")                                                 \
        for (int i_ = 0; i_ < (NIT); ++i_) {                              \
            int o_   = i_ * ((NTHR) * 16) + threadIdx.x * 16;             \
            int row_ = o_ >> 9;                                           \
            int cb_  = o_ & 511;                                          \
            gload_lds16(s_ + row_ * 512 + (cb_ ^ ((row_ & 7) << 4)),      \
                        d_ + o_);                                         \
        }                                                                 \
    } while (0)

#define UNRANK                                                            \
    int bid = blockIdx.x, rpan = 0, rem = PAN;                            \
    while (bid >= rem) { bid -= rem; ++rpan; --rem; }                     \
    const int cpan = rpan + bid;                                          \
    const bool diag = (rpan == cpan); (void)diag;

// ---- Kernel A: row L2-normalize -> bf16 reps; fp32 positives ----
__global__ __launch_bounds__(64) void knorm(const float* __restrict__ zi,
                                            const float* __restrict__ zj,
                                            unsigned short* __restrict__ reps,
                                            float* __restrict__ pos, int n) {
    const int i = blockIdx.x;
    const int lane = threadIdx.x;
    const float4 a = ((const float4*)(zi + (size_t)i * D))[lane];
    const float4 b = ((const float4*)(zj + (size_t)i * D))[lane];
    float si = a.x*a.x + a.y*a.y + a.z*a.z + a.w*a.w;
    float sj = b.x*b.x + b.y*b.y + b.z*b.z + b.w*b.w;
    float sd = a.x*b.x + a.y*b.y + a.z*b.z + a.w*b.w;
    #pragma unroll
    for (int off = 32; off; off >>= 1) {
        si += __shfl_xor(si, off);
        sj += __shfl_xor(sj, off);
        sd += __shfl_xor(sd, off);
    }
    const float inv_i = 1.0f / fmaxf(sqrtf(si), 1e-12f);
    const float inv_j = 1.0f / fmaxf(sqrtf(sj), 1e-12f);
    if (lane == 0) pos[i] = sd * inv_i * inv_j;
    ushort4 pa, pb;
    pa.x = f2bf(a.x * inv_i); pa.y = f2bf(a.y * inv_i);
    pa.z = f2bf(a.z * inv_i); pa.w = f2bf(a.w * inv_i);
    pb.x = f2bf(b.x * inv_j); pb.y = f2bf(b.y * inv_j);
    pb.z = f2bf(b.z * inv_j); pb.w = f2bf(b.w * inv_j);
    ((ushort4*)(reps + (size_t)i * D))[lane]       = pa;
    ((ushort4*)(reps + (size_t)(i + n) * D))[lane] = pb;
}

// ================= 512-thread ablation variants (RT=2, 8 waves) ============
// STG: include staging; LDSR: read B from LDS; EXPE: exp+colsum epilogue
#define KAB_BODY(STG, LDSR, EXPE)                                              \
    __shared__ unsigned short buf[2][BN * D];                                  \
    __shared__ float cs_lds[8][16][16];                                        \
    const int lane = threadIdx.x & 63;                                         \
    const int w    = threadIdx.x >> 6;                                         \
    const int lrow = lane & 15;                                                \
    const int lkb  = (lane >> 4) * 16;                                         \
    const int swz  = (lrow & 7) << 4;                                          \
    UNRANK                                                                     \
    const char* Bb = (const char*)reps + (size_t)cpan * 256 * 512;             \
    bf16x8 afrag[2][KC];                                                       \
    _Pragma("unroll")                                                          \
    for (int rt = 0; rt < 2; ++rt) {                                           \
        const char* ar = (const char*)reps                                     \
            + (size_t)(rpan * 256 + w * 32 + rt * 16 + lrow) * 512 + lkb;      \
        _Pragma("unroll")                                                      \
        for (int kc = 0; kc < KC; ++kc)                                        \
            afrag[rt][kc] = *(const bf16x8*)(ar + kc * 64);                    \
    }                                                                          \
    float rs[2][4];                                                            \
    _Pragma("unroll")                                                          \
    for (int rt = 0; rt < 2; ++rt)                                             \
        for (int e = 0; e < 4; ++e) rs[rt][e] = 0.f;                           \
    for (int rep = 0; rep < REP; ++rep) {                                      \
        if (STG) STAGE_T(&buf[0][0], Bb, 512, 2);                              \
        __syncthreads();                                                       \
        int cur = 0;                                                           \
        for (int c = 0; c < NCH; ++c) {                                        \
            if (STG && c < NCH - 1)                                            \
                STAGE_T(&buf[cur ^ 1][0], Bb + (size_t)(c + 1) * 16384, 512, 2);\
            const char* bb = (const char*)&buf[cur][0];                        \
            f32x4 acc[2][2];                                                   \
            _Pragma("unroll")                                                  \
            for (int rt = 0; rt < 2; ++rt) {                                   \
                acc[rt][0] = (f32x4){0.f,0.f,0.f,0.f};                         \
                acc[rt][1] = (f32x4){0.f,0.f,0.f,0.f};                         \
            }                                                                  \
            _Pragma("unroll")                                                  \
            for (int kc = 0; kc < KC; ++kc) {                                  \
                bf16x8 bf0, bf1;                                               \
                if (LDSR) {                                                    \
                    const int kb = (kc * 64 + lkb) ^ swz;                      \
                    bf0 = *(const bf16x8*)(bb + (lrow)      * 512 + kb);       \
                    bf1 = *(const bf16x8*)(bb + (16 + lrow) * 512 + kb);       \
                } else { bf0 = afrag[0][kc]; bf1 = afrag[1][kc]; }             \
                _Pragma("unroll")                                              \
                for (int rt = 0; rt < 2; ++rt) {                               \
                    acc[rt][0] = __builtin_amdgcn_mfma_f32_16x16x32_bf16(      \
                        afrag[rt][kc], bf0, acc[rt][0], 0, 0, 0);              \
                    acc[rt][1] = __builtin_amdgcn_mfma_f32_16x16x32_bf16(      \
                        afrag[rt][kc], bf1, acc[rt][1], 0, 0, 0);              \
                }                                                              \
            }                                                                  \
            if (EXPE) {                                                        \
                float cs0 = 0.f, cs1 = 0.f;                                    \
                _Pragma("unroll")                                              \
                for (int rt = 0; rt < 2; ++rt)                                 \
                    for (int e = 0; e < 4; ++e) {                              \
                        float e0 = __builtin_amdgcn_exp2f(acc[rt][0][e]*CEXP); \
                        float e1 = __builtin_amdgcn_exp2f(acc[rt][1][e]*CEXP); \
                        rs[rt][e] += e0 + e1;                                  \
                        cs0 += e0; cs1 += e1;                                  \
                    }                                                          \
                cs0 += __shfl_xor(cs0, 16); cs0 += __shfl_xor(cs0, 32);        \
                cs1 += __shfl_xor(cs1, 16); cs1 += __shfl_xor(cs1, 32);        \
                if (lane < 16) {                                               \
                    cs_lds[w][c * 2 + 0][lane] = cs0;                          \
                    cs_lds[w][c * 2 + 1][lane] = cs1;                          \
                }                                                              \
            } else {                                                           \
                _Pragma("unroll")                                              \
                for (int rt = 0; rt < 2; ++rt)                                 \
                    for (int e = 0; e < 4; ++e)                                \
                        rs[rt][e] += acc[rt][0][e] + acc[rt][1][e];            \
            }                                                                  \
            __syncthreads();                                                   \
            cur ^= 1;                                                          \
        }                                                                      \
    }                                                                          \
    _Pragma("unroll")                                                          \
    for (int rt = 0; rt < 2; ++rt)                                             \
        for (int e = 0; e < 4; ++e)                                            \
            for (int off = 1; off < 16; off <<= 1)                             \
                rs[rt][e] += __shfl_xor(rs[rt][e], off);                       \
    if ((lane & 15) == 0) {                                                    \
        _Pragma("unroll")                                                      \
        for (int rt = 0; rt < 2; ++rt) {                                       \
            const int rg = rpan * 256 + w * 32 + rt * 16 + (lane >> 4) * 4;    \
            f32x4 v = {rs[rt][0], rs[rt][1], rs[rt][2], rs[rt][3]};            \
            *(f32x4*)(partial + (size_t)cpan * twoN + rg) = v;                 \
        }                                                                      \
    }                                                                          \
    if (EXPE && !diag && threadIdx.x < 256) {                                  \
        const int ct  = threadIdx.x >> 4;                                      \
        const int col = threadIdx.x & 15;                                      \
        float v = 0.f;                                                         \
        _Pragma("unroll")                                                      \
        for (int ww = 0; ww < 8; ++ww) v += cs_lds[ww][ct][col];               \
        partial[(size_t)rpan * twoN + cpan * 256 + ct * 16 + col] = v;         \
    }

__global__ __launch_bounds__(512) void kab_nostage(const unsigned short* __restrict__ reps,
                                                   float* __restrict__ partial, int twoN) {
    KAB_BODY(0, 1, 1)
}
__global__ __launch_bounds__(512) void kab_nolds(const unsigned short* __restrict__ reps,
                                                 float* __restrict__ partial, int twoN) {
    KAB_BODY(1, 0, 1)
}
__global__ __launch_bounds__(512) void kab_noexp(const unsigned short* __restrict__ reps,
                                                 float* __restrict__ partial, int twoN) {
    KAB_BODY(1, 1, 0)
}
__global__ __launch_bounds__(512) void kab_r8(const unsigned short* __restrict__ reps,
                                              float* __restrict__ partial, int twoN) {
    KAB_BODY(1, 1, 1)
}

// ============ kfix: 4 waves x RT=4 (REAL output, runs last) ============
__global__ __launch_bounds__(256) void kfix(const unsigned short* __restrict__ reps,
                                            float* __restrict__ partial, int twoN) {
    __shared__ unsigned short buf[2][BN * D];   // 32 KB
    __shared__ float cs_lds[4][16][16];         // 4 KB
    const int lane = threadIdx.x & 63;
    const int w    = threadIdx.x >> 6;          // 0..3
    const int lrow = lane & 15;
    const int lkb  = (lane >> 4) * 16;
    const int swz  = (lrow & 7) << 4;
    UNRANK

    const char* Bb = (const char*)reps + (size_t)cpan * 256 * 512;
    STAGE_T(&buf[0][0], Bb, 256, 4);   // issue before A loads

    bf16x8 afrag[4][KC];
    #pragma unroll
    for (int rt = 0; rt < 4; ++rt) {
        const char* ar = (const char*)reps
            + (size_t)(rpan * 256 + w * 64 + rt * 16 + lrow) * 512 + lkb;
        #pragma unroll
        for (int kc = 0; kc < KC; ++kc)
            afrag[rt][kc] = *(const bf16x8*)(ar + kc * 64);
    }

    float rs[4][4];
    #pragma unroll
    for (int rt = 0; rt < 4; ++rt)
        #pragma unroll
        for (int e = 0; e < 4; ++e) rs[rt][e] = 0.f;

    for (int rep = 0; rep < REP; ++rep) {
        if (rep) STAGE_T(&buf[0][0], Bb, 256, 4);
        __syncthreads();
        int cur = 0;
        for (int c = 0; c < NCH; ++c) {
            if (c < NCH - 1)
                STAGE_T(&buf[cur ^ 1][0], Bb + (size_t)(c + 1) * 16384, 256, 4);
            const char* bb = (const char*)&buf[cur][0];
            f32x4 acc[4][2];
            #pragma unroll
            for (int rt = 0; rt < 4; ++rt) {
                acc[rt][0] = (f32x4){0.f,0.f,0.f,0.f};
                acc[rt][1] = (f32x4){0.f,0.f,0.f,0.f};
            }
            #pragma unroll
            for (int kc = 0; kc < KC; ++kc) {
                const int kb = (kc * 64 + lkb) ^ swz;
                bf16x8 bf0 = *(const bf16x8*)(bb + (lrow)      * 512 + kb);
                bf16x8 bf1 = *(const bf16x8*)(bb + (16 + lrow) * 512 + kb);
                #pragma unroll
                for (int rt = 0; rt < 4; ++rt) {
                    acc[rt][0] = __builtin_amdgcn_mfma_f32_16x16x32_bf16(
                        afrag[rt][kc], bf0, acc[rt][0], 0, 0, 0);
                    acc[rt][1] = __builtin_amdgcn_mfma_f32_16x16x32_bf16(
                        afrag[rt][kc], bf1, acc[rt][1], 0, 0, 0);
                }
            }
            float cs0 = 0.f, cs1 = 0.f;
            #pragma unroll
            for (int rt = 0; rt < 4; ++rt)
                #pragma unroll
                for (int e = 0; e < 4; ++e) {
                    float e0 = __builtin_amdgcn_exp2f(acc[rt][0][e] * CEXP);
                    float e1 = __builtin_amdgcn_exp2f(acc[rt][1][e] * CEXP);
                    rs[rt][e] += e0 + e1;
                    cs0 += e0; cs1 += e1;
                }
            if (!diag) {
                cs0 += __shfl_xor(cs0, 16); cs0 += __shfl_xor(cs0, 32);
                cs1 += __shfl_xor(cs1, 16); cs1 += __shfl_xor(cs1, 32);
                if (lane < 16) {
                    cs_lds[w][c * 2 + 0][lane] = cs0;   // single-pass values
                    cs_lds[w][c * 2 + 1][lane] = cs1;
                }
            }
            __syncthreads();
            cur ^= 1;
        }
    }

    // rowsum: rs holds REP=4 identical passes -> exact *0.25f
    #pragma unroll
    for (int rt = 0; rt < 4; ++rt)
        #pragma unroll
        for (int e = 0; e < 4; ++e)
            #pragma unroll
            for (int off = 1; off < 16; off <<= 1)
                rs[rt][e] += __shfl_xor(rs[rt][e], off);
    if ((lane & 15) == 0) {
        #pragma unroll
        for (int rt = 0; rt < 4; ++rt) {
            const int rg = rpan * 256 + w * 64 + rt * 16 + (lane >> 4) * 4;
            f32x4 v = {rs[rt][0]*0.25f, rs[rt][1]*0.25f, rs[rt][2]*0.25f, rs[rt][3]*0.25f};
            *(f32x4*)(partial + (size_t)cpan * twoN + rg) = v;
        }
    }
    // colsum: cs_lds holds single-pass values -> no scale
    if (!diag) {
        const int ct  = threadIdx.x >> 4;
        const int col = threadIdx.x & 15;
        float v = 0.f;
        #pragma unroll
        for (int ww = 0; ww < 4; ++ww) v += cs_lds[ww][ct][col];
        partial[(size_t)rpan * twoN + cpan * 256 + ct * 16 + col] = v;
    }
}

// ---- finals ----
__global__ __launch_bounds__(256) void kfinal1(const float* __restrict__ partial,
                                               const float* __restrict__ pos,
                                               float* __restrict__ bsum,
                                               int twoN, int n) {
    __shared__ float red[256];
    const int r = blockIdx.x * 256 + threadIdx.x;
    float s = 0.f;
    if (r < twoN) {
        float dsum = 0.f;
        #pragma unroll
        for (int p = 0; p < SLOTS; ++p) dsum += partial[(size_t)p * twoN + r];
        dsum -= E2;
        const float q = pos[r < n ? r : r - n];
        s = logf(dsum) - 2.0f * q;
    }
    red[threadIdx.x] = s;
    __syncthreads();
    #pragma unroll
    for (int off = 128; off; off >>= 1) {
        if (threadIdx.x < off) red[threadIdx.x] += red[threadIdx.x + off];
        __syncthreads();
    }
    if (threadIdx.x == 0) bsum[blockIdx.x] = red[0];
}

__global__ __launch_bounds__(64) void kfinal2(const float* __restrict__ bsum,
                                              float* __restrict__ out, int twoN) {
    float s = threadIdx.x < FBLK ? bsum[threadIdx.x] : 0.f;
    #pragma unroll
    for (int off = 32; off; off >>= 1) s += __shfl_xor(s, off);
    if (threadIdx.x == 0) out[0] = s / (float)twoN;
}

extern "C" void kernel_launch(void* const* d_in, const int* in_sizes, int n_in,
                              void* d_out, int out_size, void* d_ws, size_t ws_size,
                              hipStream_t stream) {
    const float* zi = (const float*)d_in[0];
    const float* zj = (const float*)d_in[1];
    const int n    = in_sizes[0] / D;   // 4096
    const int twoN = 2 * n;             // 8192

    unsigned short* reps = (unsigned short*)d_ws;
    float* pos     = (float*)((char*)d_ws + (size_t)twoN * D * 2);
    float* partial = pos + n;
    float* bsum    = partial + (size_t)SLOTS * twoN;
    float* out     = (float*)d_out;

    knorm<<<n, 64, 0, stream>>>(zi, zj, reps, pos, n);
    // ablation dummies (their partial writes are fully overwritten by kfix)
    kab_nostage<<<NBLK, 512, 0, stream>>>(reps, partial, twoN);
    kab_nolds  <<<NBLK, 512, 0, stream>>>(reps, partial, twoN);
    kab_noexp  <<<NBLK, 512, 0, stream>>>(reps, partial, twoN);
    kab_r8     <<<NBLK, 512, 0, stream>>>(reps, partial, twoN);
    // real computation
    kfix<<<NBLK, 256, 0, stream>>>(reps, partial, twoN);
    kfinal1<<<FBLK, 256, 0, stream>>>(partial, pos, bsum, twoN, n);
    kfinal2<<<1, 64, 0, stream>>>(bsum, out, twoN);
}

// Round 11
// 84.235 us; speedup vs baseline: 5.9243x; 5.9243x over previous
//
#include <hip/hip_runtime.h>
#include <hip/hip_bf16.h>

// NT-Xent loss, fused + symmetric. N=4096, D=256, T=0.5.
// Panel-pair blocks (528). 4 waves x 64 rows (RT=4). B half-panel (128 cols,
// 64KB) staged ONCE per half; main loop is BARRIER-FREE (R10 ablation showed
// phase costs additive -> lockstep barriers serialized MFMA/LDS/VALU pipes).
// d_ws: [reps bf16 2N*D | pos f32 N | partial f32 SLOTS*2N | bsum f32 32]
// loss_i = log(sum_j exp(sim_ij/T) - e^2) - pos_i/T ; out = mean(loss)

#define D      256
#define KC     8            // K-chunks of 32 elems (D/32)
#define RT     4            // row-tiles per wave -> 64 rows/wave
#define PAN    32           // 256-row panels
#define NBLK   (PAN * (PAN + 1) / 2)   // 528
#define SLOTS  32
#define CEXP   2.885390081777926f  // 1/(T*ln2): exp(x/T) = 2^(x*CEXP)
#define E2     7.38905609893065f   // exp(1/T), diagonal term
#define FBLK   32

typedef __bf16 bf16x8 __attribute__((ext_vector_type(8)));
typedef float  f32x4  __attribute__((ext_vector_type(4)));
typedef __attribute__((address_space(1))) const unsigned int* gas_t;
typedef __attribute__((address_space(3))) unsigned int*       las_t;

static __device__ __forceinline__ void gload_lds16(const void* g, void* l) {
    __builtin_amdgcn_global_load_lds((gas_t)(uintptr_t)g, (las_t)(uintptr_t)l, 16, 0, 0);
}

static __device__ __forceinline__ unsigned short f2bf(float x) {
    union { float f; unsigned u; } v; v.f = x;
    unsigned r = v.u + 0x7fffu + ((v.u >> 16) & 1u);   // RNE
    return (unsigned short)(r >> 16);
}

// Stage 64KB (128 rows x 512B) global->LDS, 256 threads x 16 iters x 16B.
// Linear LDS dest; source pre-swizzled so swizzled ds_reads see correct data.
#define STAGE64(bufp, srcp)                                               \
    do {                                                                  \
        const char* s_ = (const char*)(srcp);                             \
        char* d_ = (char*)(bufp);                                         \
        _Pragma("unroll")                                                 \
        for (int i_ = 0; i_ < 16; ++i_) {                                 \
            int o_   = i_ * 4096 + threadIdx.x * 16;                      \
            int row_ = o_ >> 9;                                           \
            int cb_  = o_ & 511;                                          \
            gload_lds16(s_ + row_ * 512 + (cb_ ^ ((row_ & 7) << 4)),      \
                        d_ + o_);                                         \
        }                                                                 \
    } while (0)

// ---- Kernel A: row L2-normalize -> bf16 reps; fp32 positives ----
__global__ __launch_bounds__(64) void knorm(const float* __restrict__ zi,
                                            const float* __restrict__ zj,
                                            unsigned short* __restrict__ reps,
                                            float* __restrict__ pos, int n) {
    const int i = blockIdx.x;
    const int lane = threadIdx.x;
    const float4 a = ((const float4*)(zi + (size_t)i * D))[lane];
    const float4 b = ((const float4*)(zj + (size_t)i * D))[lane];
    float si = a.x*a.x + a.y*a.y + a.z*a.z + a.w*a.w;
    float sj = b.x*b.x + b.y*b.y + b.z*b.z + b.w*b.w;
    float sd = a.x*b.x + a.y*b.y + a.z*b.z + a.w*b.w;
    #pragma unroll
    for (int off = 32; off; off >>= 1) {
        si += __shfl_xor(si, off);
        sj += __shfl_xor(sj, off);
        sd += __shfl_xor(sd, off);
    }
    const float inv_i = 1.0f / fmaxf(sqrtf(si), 1e-12f);
    const float inv_j = 1.0f / fmaxf(sqrtf(sj), 1e-12f);
    if (lane == 0) pos[i] = sd * inv_i * inv_j;
    ushort4 pa, pb;
    pa.x = f2bf(a.x * inv_i); pa.y = f2bf(a.y * inv_i);
    pa.z = f2bf(a.z * inv_i); pa.w = f2bf(a.w * inv_i);
    pb.x = f2bf(b.x * inv_j); pb.y = f2bf(b.y * inv_j);
    pb.z = f2bf(b.z * inv_j); pb.w = f2bf(b.w * inv_j);
    ((ushort4*)(reps + (size_t)i * D))[lane]       = pa;
    ((ushort4*)(reps + (size_t)(i + n) * D))[lane] = pb;
}

// ---- Kernel B: symmetric panel-pair exp-rowsum, barrier-free main loop ----
__global__ __launch_bounds__(256, 2) void krowsum(const unsigned short* __restrict__ reps,
                                                  float* __restrict__ partial, int twoN) {
    __shared__ unsigned short buf[128 * D];     // 64 KB: half B panel (128 cols)
    __shared__ float cs_lds[4][16][16];         // [wave][gc*2+tile][col], 4 KB
    const int lane = threadIdx.x & 63;
    const int w    = threadIdx.x >> 6;          // 0..3
    const int lrow = lane & 15;
    const int lkb  = (lane >> 4) * 16;
    const int swz  = (lrow & 7) << 4;

    // unrank blockIdx -> (rpan, cpan), rpan <= cpan
    int bid = blockIdx.x, rpan = 0, rem = PAN;
    while (bid >= rem) { bid -= rem; ++rpan; --rem; }
    const int cpan = rpan + bid;
    const bool diag = (rpan == cpan);

    const char* Bb = (const char*)reps + (size_t)cpan * 256 * 512;
    STAGE64(&buf[0], Bb);                       // half 0 in flight

    // A fragments: 64 rows/wave, direct global (completes under stage)
    bf16x8 afrag[RT][KC];
    #pragma unroll
    for (int rt = 0; rt < RT; ++rt) {
        const char* ar = (const char*)reps
            + (size_t)(rpan * 256 + w * 64 + rt * 16 + lrow) * 512 + lkb;
        #pragma unroll
        for (int kc = 0; kc < KC; ++kc)
            afrag[rt][kc] = *(const bf16x8*)(ar + kc * 64);
    }

    float rs[RT][4];
    #pragma unroll
    for (int rt = 0; rt < RT; ++rt)
        #pragma unroll
        for (int e = 0; e < 4; ++e) rs[rt][e] = 0.f;

    for (int h = 0; h < 2; ++h) {
        if (h) {
            __syncthreads();                    // all waves done reading half 0
            STAGE64(&buf[0], Bb + 65536);       // overwrite with half 1
        }
        __syncthreads();                        // staged data visible (vmcnt drain)
        // ---- 4 chunks of 32 cols, NO barriers: pipes free-flow ----
        #pragma unroll
        for (int c = 0; c < 4; ++c) {
            const int gc = h * 4 + c;
            const char* bb = (const char*)&buf[0] + c * 32 * 512;
            f32x4 acc[RT][2];
            #pragma unroll
            for (int rt = 0; rt < RT; ++rt) {
                acc[rt][0] = (f32x4){0.f, 0.f, 0.f, 0.f};
                acc[rt][1] = (f32x4){0.f, 0.f, 0.f, 0.f};
            }
            #pragma unroll
            for (int kc = 0; kc < KC; ++kc) {
                const int kb = (kc * 64 + lkb) ^ swz;
                bf16x8 bf0 = *(const bf16x8*)(bb + (lrow)      * 512 + kb);
                bf16x8 bf1 = *(const bf16x8*)(bb + (16 + lrow) * 512 + kb);
                #pragma unroll
                for (int rt = 0; rt < RT; ++rt) {
                    acc[rt][0] = __builtin_amdgcn_mfma_f32_16x16x32_bf16(
                        afrag[rt][kc], bf0, acc[rt][0], 0, 0, 0);
                    acc[rt][1] = __builtin_amdgcn_mfma_f32_16x16x32_bf16(
                        afrag[rt][kc], bf1, acc[rt][1], 0, 0, 0);
                }
            }
            // C/D layout: col = lane&15, row = (lane>>4)*4 + e  [m89]
            float cs0 = 0.f, cs1 = 0.f;
            #pragma unroll
            for (int rt = 0; rt < RT; ++rt)
                #pragma unroll
                for (int e = 0; e < 4; ++e) {
                    float e0 = __builtin_amdgcn_exp2f(acc[rt][0][e] * CEXP);
                    float e1 = __builtin_amdgcn_exp2f(acc[rt][1][e] * CEXP);
                    rs[rt][e] += e0 + e1;
                    cs0 += e0; cs1 += e1;
                }
            if (!diag) {
                cs0 += __shfl_xor(cs0, 16); cs0 += __shfl_xor(cs0, 32);
                cs1 += __shfl_xor(cs1, 16); cs1 += __shfl_xor(cs1, 32);
                if (lane < 16) {
                    cs_lds[w][gc * 2 + 0][lane] = cs0;
                    cs_lds[w][gc * 2 + 1][lane] = cs1;
                }
            }
        }
    }
    __syncthreads();                            // publish cs_lds

    // ---- rowsum: reduce 16 col-lanes, write partial[cpan][row] (f32x4) ----
    #pragma unroll
    for (int rt = 0; rt < RT; ++rt)
        #pragma unroll
        for (int e = 0; e < 4; ++e)
            #pragma unroll
            for (int off = 1; off < 16; off <<= 1)
                rs[rt][e] += __shfl_xor(rs[rt][e], off);
    if ((lane & 15) == 0) {
        #pragma unroll
        for (int rt = 0; rt < RT; ++rt) {
            const int rg = rpan * 256 + w * 64 + rt * 16 + (lane >> 4) * 4;
            f32x4 v = {rs[rt][0], rs[rt][1], rs[rt][2], rs[rt][3]};
            *(f32x4*)(partial + (size_t)cpan * twoN + rg) = v;
        }
    }

    // ---- colsum: cross-wave sum (4 waves), write partial[rpan][col] ----
    if (!diag) {
        const int ct  = threadIdx.x >> 4;       // gc*2+tile, 0..15
        const int col = threadIdx.x & 15;
        float v = 0.f;
        #pragma unroll
        for (int ww = 0; ww < 4; ++ww) v += cs_lds[ww][ct][col];
        const int gcol = cpan * 256 + (ct >> 1) * 32 + (ct & 1) * 16 + col;
        partial[(size_t)rpan * twoN + gcol] = v;
    }
}

// ---- Kernel C1: per-row loss, block partial sums ----
__global__ __launch_bounds__(256) void kfinal1(const float* __restrict__ partial,
                                               const float* __restrict__ pos,
                                               float* __restrict__ bsum,
                                               int twoN, int n) {
    __shared__ float red[256];
    const int r = blockIdx.x * 256 + threadIdx.x;
    float s = 0.f;
    if (r < twoN) {
        float dsum = 0.f;
        #pragma unroll
        for (int p = 0; p < SLOTS; ++p) dsum += partial[(size_t)p * twoN + r];
        dsum -= E2;
        const float q = pos[r < n ? r : r - n];
        s = logf(dsum) - 2.0f * q;              // pos/T with T=0.5
    }
    red[threadIdx.x] = s;
    __syncthreads();
    #pragma unroll
    for (int off = 128; off; off >>= 1) {
        if (threadIdx.x < off) red[threadIdx.x] += red[threadIdx.x + off];
        __syncthreads();
    }
    if (threadIdx.x == 0) bsum[blockIdx.x] = red[0];
}

// ---- Kernel C2: final mean ----
__global__ __launch_bounds__(64) void kfinal2(const float* __restrict__ bsum,
                                              float* __restrict__ out, int twoN) {
    float s = threadIdx.x < FBLK ? bsum[threadIdx.x] : 0.f;
    #pragma unroll
    for (int off = 32; off; off >>= 1) s += __shfl_xor(s, off);
    if (threadIdx.x == 0) out[0] = s / (float)twoN;
}

extern "C" void kernel_launch(void* const* d_in, const int* in_sizes, int n_in,
                              void* d_out, int out_size, void* d_ws, size_t ws_size,
                              hipStream_t stream) {
    const float* zi = (const float*)d_in[0];
    const float* zj = (const float*)d_in[1];
    const int n    = in_sizes[0] / D;   // 4096
    const int twoN = 2 * n;             // 8192

    unsigned short* reps = (unsigned short*)d_ws;                   // 4 MB
    float* pos     = (float*)((char*)d_ws + (size_t)twoN * D * 2);  // N f32
    float* partial = pos + n;                                       // SLOTS*2N f32
    float* bsum    = partial + (size_t)SLOTS * twoN;                // FBLK f32
    float* out     = (float*)d_out;

    knorm<<<n, 64, 0, stream>>>(zi, zj, reps, pos, n);
    krowsum<<<NBLK, 256, 0, stream>>>(reps, partial, twoN);
    kfinal1<<<FBLK, 256, 0, stream>>>(partial, pos, bsum, twoN, n);
    kfinal2<<<1, 64, 0, stream>>>(bsum, out, twoN);
}